// Round 3
// baseline (89.485 us; speedup 1.0000x reference)
//
#include <hip/hip_runtime.h>
#include <hip/hip_bf16.h>

// Problem constants (fixed by setup_inputs): B=4096, d=128, M=8192, C=16
#define B_ROWS 4096
#define D_K    128
#define M_ROWS 8192
#define N_TOT  12288   // B_ROWS + M_ROWS
#define NJT    96      // N_TOT / 128  (j-tiles of 128 G-rows)
#define NJT_B  32      // B_ROWS / 128 (in-batch j-tiles)
#define NCHUNK 16      // j-chunks (grid.x)
#define JT_PER_CHUNK 6 // 96 / 16

typedef __attribute__((ext_vector_type(8))) short short8;
typedef __attribute__((ext_vector_type(4))) float floatx4;

__device__ __forceinline__ void load_lds16(const __hip_bfloat16* g, __hip_bfloat16* l) {
    __builtin_amdgcn_global_load_lds(
        (const __attribute__((address_space(1))) void*)g,
        (__attribute__((address_space(3))) void*)l, 16, 0, 0);
}

// ---------------------------------------------------------------------------
// Kernel 1: normalize rows of f / f_neg into bf16 G[N_TOT][D_K].
// One wave per row; lane holds 2 floats.
// ---------------------------------------------------------------------------
__global__ __launch_bounds__(256) void nrm_kernel(
    const float* __restrict__ f, const float* __restrict__ fneg,
    __hip_bfloat16* __restrict__ G)
{
    const int wave = threadIdx.x >> 6;
    const int lane = threadIdx.x & 63;
    const int row  = blockIdx.x * 4 + wave;           // grid exact: 3072*4
    const float* src = (row < B_ROWS) ? (f + (size_t)row * D_K)
                                      : (fneg + (size_t)(row - B_ROWS) * D_K);
    float2 v = *reinterpret_cast<const float2*>(src + lane * 2);
    float ss = v.x * v.x + v.y * v.y;
    #pragma unroll
    for (int m = 1; m < 64; m <<= 1) ss += __shfl_xor(ss, m, 64);
    const float scale = 1.0f / fmaxf(sqrtf(ss), 1e-8f);   // 1/max(||x||, EPS)
    __hip_bfloat162 o;
    o.x = __float2bfloat16(v.x * scale);
    o.y = __float2bfloat16(v.y * scale);
    *reinterpret_cast<__hip_bfloat162*>(G + (size_t)row * D_K + lane * 2) = o;
}

// ---------------------------------------------------------------------------
// Kernel 2: staged sim + exp + row-accumulate.
// Grid (NCHUNK=16, 32). Block = 256 thr = 4 waves; block tile 128i x 128j.
// Wave (wi,wj) owns 64x64: acc[4][4] fragments of mfma_f32_16x16x32_bf16.
// A fragments register-resident (loaded once from L2, gather is one-time).
// B j-tile (128 rows x 256B = 32KB) staged to LDS via global_load_lds w=16,
// double-buffered; source pre-swizzled (col ^ (row&7)) so swizzled
// ds_read_b128 fragment reads are bank-uniform (8 lanes/bank-group = b128
// floor). One barrier per j-tile; next tile's stage issued before compute.
// Fragment layouts as verified in R1/R2:
//   A/B: row = lane&15, k = (lane>>4)*8 + e (contiguous bf16x8)
//   C/D: col(j) = lane&15, row(i) = (lane>>4)*4 + reg
// ---------------------------------------------------------------------------
__global__ __launch_bounds__(256, 2) void sim_kernel(
    const __hip_bfloat16* __restrict__ G, const int* __restrict__ labels,
    float* __restrict__ part_d, float* __restrict__ part_p)
{
    __shared__ __hip_bfloat16 Bs[2][128 * 128];   // 2 x 32KB

    const int jc   = blockIdx.x;          // 0..15
    const int it   = blockIdx.y;          // 0..31
    const int tid  = threadIdx.x;
    const int wave = tid >> 6;
    const int lane = tid & 63;
    const int wi   = wave >> 1;           // 0..1
    const int wj   = wave & 1;            // 0..1
    const int i0   = it * 128 + wi * 64;

    const int r16 = lane & 15;
    const int grp = lane >> 4;

    // ---- resident A fragments: [a][ks], 4x4 short8 ----
    const __hip_bfloat16* Arow = G + (size_t)(i0 + r16) * D_K + grp * 8;
    short8 afr[4][4];
    #pragma unroll
    for (int a = 0; a < 4; ++a)
        #pragma unroll
        for (int ks = 0; ks < 4; ++ks)
            afr[a][ks] = *reinterpret_cast<const short8*>(
                Arow + (size_t)a * 16 * D_K + ks * 32);

    // labels for my 16 output rows
    int myl[4][4];
    #pragma unroll
    for (int a = 0; a < 4; ++a)
        #pragma unroll
        for (int r = 0; r < 4; ++r)
            myl[a][r] = labels[i0 + a * 16 + grp * 4 + r];

    float dsum[4][4], psum[4][4];
    #pragma unroll
    for (int a = 0; a < 4; ++a)
        #pragma unroll
        for (int r = 0; r < 4; ++r) { dsum[a][r] = 0.f; psum[a][r] = 0.f; }

    // per-lane staging source offsets (elements within a 128x128 tile):
    // linear LDS byte o = (wave*8+s)*1024 + lane*16 -> row=o>>8, col=(o>>4)&15
    // source column pre-swizzled: sc = col ^ (row&7)
    int srcoff[8];
    #pragma unroll
    for (int s = 0; s < 8; ++s) {
        const int o   = (wave * 8 + s) * 1024 + lane * 16;
        const int row = o >> 8;
        const int col = (o >> 4) & 15;
        const int sc  = col ^ (row & 7);
        srcoff[s] = row * D_K + sc * 8;
    }

    // ---- prologue: stage first tile into buf 0 ----
    {
        const __hip_bfloat16* src = G + (size_t)(jc * JT_PER_CHUNK) * 128 * D_K;
        #pragma unroll
        for (int s = 0; s < 8; ++s)
            load_lds16(src + srcoff[s], &Bs[0][(wave * 8 + s) * 512]);
    }

    for (int t = 0; t < JT_PER_CHUNK; ++t) {
        const int jt  = jc * JT_PER_CHUNK + t;
        const int cur = t & 1;
        __syncthreads();   // drains vmcnt(0): buf[cur] staged; prev compute done

        if (t + 1 < JT_PER_CHUNK) {
            const __hip_bfloat16* src = G + (size_t)(jt + 1) * 128 * D_K;
            #pragma unroll
            for (int s = 0; s < 8; ++s)
                load_lds16(src + srcoff[s], &Bs[cur ^ 1][(wave * 8 + s) * 512]);
        }

        const int  j0  = jt * 128 + wj * 64;
        const bool inb = (jt < NJT_B);
        int jl[4];
        if (inb) {
            #pragma unroll
            for (int b = 0; b < 4; ++b) jl[b] = labels[j0 + b * 16 + r16];
        }

        floatx4 acc[4][4];
        #pragma unroll
        for (int a = 0; a < 4; ++a)
            #pragma unroll
            for (int b = 0; b < 4; ++b)
                acc[a][b] = (floatx4){0.f, 0.f, 0.f, 0.f};

        const char* base = (const char*)&Bs[cur][0];
        #pragma unroll
        for (int ks = 0; ks < 4; ++ks) {
            short8 bfr[4];
            #pragma unroll
            for (int b = 0; b < 4; ++b) {
                const int jloc = wj * 64 + b * 16 + r16;
                const int slot = (ks * 4 + grp) ^ (jloc & 7);
                bfr[b] = *reinterpret_cast<const short8*>(
                    base + jloc * 256 + slot * 16);
            }
            #pragma unroll
            for (int a = 0; a < 4; ++a)
                #pragma unroll
                for (int b = 0; b < 4; ++b)
                    acc[a][b] = __builtin_amdgcn_mfma_f32_16x16x32_bf16(
                        afr[a][ks], bfr[b], acc[a][b], 0, 0, 0);
        }

        if (inb) {
            #pragma unroll
            for (int a = 0; a < 4; ++a) {
                #pragma unroll
                for (int r = 0; r < 4; ++r) {
                    const int ig = i0 + a * 16 + grp * 4 + r;
                    #pragma unroll
                    for (int b = 0; b < 4; ++b) {
                        const float v  = acc[a][b][r];
                        const int   jg = j0 + b * 16 + r16;
                        const bool self = (jg == ig);
                        dsum[a][r] += self ? 0.f : __expf(v);
                        psum[a][r] += (!self && jl[b] == myl[a][r]) ? v : 0.f;
                    }
                }
            }
        } else {
            #pragma unroll
            for (int a = 0; a < 4; ++a)
                #pragma unroll
                for (int r = 0; r < 4; ++r)
                    #pragma unroll
                    for (int b = 0; b < 4; ++b)
                        dsum[a][r] += __expf(acc[a][b][r]);
        }
    }

    // single 16-lane reduce per accumulator slot
    #pragma unroll
    for (int a = 0; a < 4; ++a) {
        #pragma unroll
        for (int r = 0; r < 4; ++r) {
            #pragma unroll
            for (int m = 1; m < 16; m <<= 1) {
                dsum[a][r] += __shfl_xor(dsum[a][r], m, 64);
                psum[a][r] += __shfl_xor(psum[a][r], m, 64);
            }
        }
    }
    if (r16 == 0) {
        #pragma unroll
        for (int a = 0; a < 4; ++a) {
            #pragma unroll
            for (int r = 0; r < 4; ++r) {
                const int row = i0 + a * 16 + grp * 4 + r;
                const size_t idx = (size_t)(jc * 2 + wj) * B_ROWS + row;
                part_d[idx] = dsum[a][r];
                part_p[idx] = psum[a][r];
            }
        }
    }
}

// ---------------------------------------------------------------------------
// Kernel 3: finalize. 16 blocks x 256 thr. Per-wave LDS histograms (low
// contention), per-row loss, block reduce, atomicAdd mean into out.
// ---------------------------------------------------------------------------
__global__ __launch_bounds__(256) void fin_kernel(
    const float* __restrict__ part_d, const float* __restrict__ part_p,
    const int* __restrict__ labels, float* __restrict__ out)
{
    const int tid  = threadIdx.x;
    const int wave = tid >> 6;
    const int lane = tid & 63;
    const int i    = blockIdx.x * 256 + tid;

    __shared__ int lh[4][16];
    if (lane < 16) lh[wave][lane] = 0;
    __syncthreads();
    for (int j = tid; j < B_ROWS; j += 256) atomicAdd(&lh[wave][labels[j]], 1);
    __syncthreads();

    float ds = 0.f, ps = 0.f;
    #pragma unroll
    for (int c = 0; c < 2 * NCHUNK; ++c) {
        ds += part_d[(size_t)c * B_ROWS + i];
        ps += part_p[(size_t)c * B_ROWS + i];
    }
    const int  l    = labels[i];
    const float npos = (float)(lh[0][l] + lh[1][l] + lh[2][l] + lh[3][l] - 1);
    float loss = __logf(ds) - ps / npos;
    #pragma unroll
    for (int m = 1; m < 64; m <<= 1) loss += __shfl_xor(loss, m, 64);
    __shared__ float w4[4];
    if (lane == 0) w4[wave] = loss;
    __syncthreads();
    if (tid == 0)
        atomicAdd(out, (w4[0] + w4[1] + w4[2] + w4[3]) * (1.0f / (float)B_ROWS));
}

// ---------------------------------------------------------------------------
extern "C" void kernel_launch(void* const* d_in, const int* in_sizes, int n_in,
                              void* d_out, int out_size, void* d_ws, size_t ws_size,
                              hipStream_t stream) {
    const float* f      = (const float*)d_in[0];
    const float* fneg   = (const float*)d_in[1];
    const int*   labels = (const int*)d_in[2];
    float*       out    = (float*)d_out;

    char* ws = (char*)d_ws;
    // Workspace layout (bytes):
    //   G      : 12288*128*2 = 3,145,728
    //   part_d : 32*4096*4   =   524,288
    //   part_p : 32*4096*4   =   524,288
    __hip_bfloat16* G      = (__hip_bfloat16*)(ws);
    float*          part_d = (float*)(ws + 3145728);
    float*          part_p = (float*)(ws + 3145728 + 524288);

    hipMemsetAsync(out, 0, sizeof(float), stream);

    nrm_kernel<<<N_TOT / 4, 256, 0, stream>>>(f, fneg, G);

    dim3 gridS(NCHUNK, 32);   // (16, 32) = 512 blocks, 2/CU
    sim_kernel<<<gridS, 256, 0, stream>>>(G, labels, part_d, part_p);

    fin_kernel<<<NCHUNK, 256, 0, stream>>>(part_d, part_p, labels, out);
}